// Round 14
// baseline (677.142 us; speedup 1.0000x reference)
//
#include <hip/hip_runtime.h>
#include <stdint.h>

#define M_DIM 512
#define K_DIM 8192
#define N_DIM 14336
#define NGRP  64      // K / 128 groups
#define BN    32      // N columns per workgroup (halved champion)

typedef int   i32x4  __attribute__((ext_vector_type(4)));
typedef int   i32x16 __attribute__((ext_vector_type(16)));
typedef float f32x4  __attribute__((ext_vector_type(4)));

// ---------------- Kernel 1: per-row dynamic int8 quantization ----------------
// Writes qA in MFMA-fragment-native layout:
//   qA[((g*16 + tile)*4 + ks)*1024 + l31*32 + lhi*16 + b]
// where row = tile*32 + l31, k = g*128 + ks*32 + lhi*16 + b.
__global__ __launch_bounds__(256) void quant_rows(const float* __restrict__ A,
                                                  uint8_t* __restrict__ qA,
                                                  float* __restrict__ s1)
{
    const int row  = blockIdx.x;
    const int tid  = threadIdx.x;
    const int tile = row >> 5;
    const int l31  = row & 31;
    const f32x4* src = (const f32x4*)(A + (size_t)row * K_DIM) + tid;

    f32x4 v[8];
#pragma unroll
    for (int i = 0; i < 8; ++i) v[i] = src[i * 256];

    float m = 0.0f;
#pragma unroll
    for (int i = 0; i < 8; ++i)
        m = fmaxf(m, fmaxf(fmaxf(fabsf(v[i].x), fabsf(v[i].y)),
                           fmaxf(fabsf(v[i].z), fabsf(v[i].w))));
#pragma unroll
    for (int off = 32; off > 0; off >>= 1)
        m = fmaxf(m, __shfl_xor(m, off));

    __shared__ float wmax[4];
    if ((tid & 63) == 0) wmax[tid >> 6] = m;
    __syncthreads();
    const float gm = fmaxf(fmaxf(wmax[0], wmax[1]), fmaxf(wmax[2], wmax[3]));
    const float s = gm / 127.0f;   // exact fp32 division, matches reference
    if (tid == 0) s1[row] = s;

#pragma unroll
    for (int i = 0; i < 8; ++i) {
        const int k0  = 4 * (tid + 256 * i);
        const int g   = k0 >> 7;
        const int ks  = (k0 >> 5) & 3;
        const int lhi = (k0 >> 4) & 1;
        const int b   = k0 & 15;
        uint32_t p = 0;
#pragma unroll
        for (int j = 0; j < 4; ++j) {
            float q = rintf(v[i][j] / s);             // round-half-even = np.round
            q = fminf(fmaxf(q, -128.0f), 127.0f);
            p |= ((uint32_t)(uint8_t)(int8_t)(int)q) << (8 * j);
        }
        *(uint32_t*)(qA + (size_t)(g * 16 + tile) * 4096 + ks * 1024
                        + l31 * 32 + lhi * 16 + b) = p;
    }
}

// ---------------- Kernel 2: fused W4A8 GEMM (champion skeleton @ BN=32) -----
// BM=512 (8 waves), BN=32, grid 448, LDS 64 KB -> 2 WGs/CU: two independent
// barrier domains per CU interleave their DMA/pack/MFMA phases (lockstep
// breaker), while halved per-wave state (facc 32, bf 16) gives real headroom
// under the 128-VGPR/4-wave-per-SIMD cap. All ordering / vmcnt discipline is
// the 184 µs champion's, with counts rescaled (body vmcnt 12->10, prologue
// 4->2).

#define DMA_GROUP(BUF, G) do {                                                 \
    _Pragma("unroll")                                                          \
    for (int j_ = 0; j_ < 2; ++j_) {                                           \
        const int idx_ = j_ * 512 + tid;   /* 16B chunk: k=idx>>3, cq=idx&7 */ \
        const int k_   = idx_ >> 3;                                            \
        const int c8_  = idx_ & 7;                                             \
        const int* gsrc_ = w4 + (size_t)((G) * 128 + k_) * N_DIM + n0 + c8_*4; \
        __builtin_amdgcn_global_load_lds(                                      \
            (const __attribute__((address_space(1))) void*)gsrc_,              \
            (__attribute__((address_space(3))) void*)&raw[BUF][(j_*512 + wv*64)*4], \
            16, 0, 0);                                                         \
    }                                                                          \
} while (0)

// pack raw[RBUF] (int32 [128k][32n]) -> pk[PBUF] (int8 col-major, swizzled)
// threads 0..255 only: c4 = tid&7 (col quad), kq = tid>>3 (k quad 0..31)
#define PACK_GROUP(PBUF, RBUF) do {                                            \
    i32x4 r_[4];                                                               \
    _Pragma("unroll")                                                          \
    for (int j_ = 0; j_ < 4; ++j_)                                             \
        r_[j_] = *(const i32x4*)&raw[RBUF][(kq * 4 + j_) * 32 + c4 * 4];       \
    _Pragma("unroll")                                                          \
    for (int c_ = 0; c_ < 4; ++c_) {                                           \
        const int col_ = c4 * 4 + c_;                                          \
        uint32_t d_ =  ((uint32_t)(r_[0][c_] - 8) & 0xFFu)                     \
                    | (((uint32_t)(r_[1][c_] - 8) & 0xFFu) << 8)               \
                    | (((uint32_t)(r_[2][c_] - 8) & 0xFFu) << 16)              \
                    | (((uint32_t)(r_[3][c_] - 8) & 0xFFu) << 24);             \
        *(uint32_t*)&pk[PBUF][col_ * 128 + ((kq * 4) ^ ((col_ & 7) << 4))] = d_; \
    }                                                                          \
} while (0)

#define BODY(G, RP, WP, ACUR, ANXT) do {                                       \
    /* 1: issue DMA for G+2 (champion order: DMA first) */                     \
    { const int gd_ = ((G) + 2 < NGRP) ? (G) + 2 : NGRP - 1;                   \
      DMA_GROUP(((G) + 2) % 3, gd_); }                                         \
    /* 2: B fragments + group scale from LDS */                                \
    i32x4 bf_[4];                                                              \
    _Pragma("unroll")                                                          \
    for (int ks = 0; ks < 4; ++ks)                                             \
        bf_[ks] = *(const i32x4*)&pk[RP][l31 * 128                             \
                        + ((ks*32 + lhi*16) ^ ((l31 & 7) << 4))];              \
    const float sg_ = sgl[(G) * 32 + l31];                                     \
    /* 3: prefetch A fragments for G+1 */                                      \
    { const int gn_ = ((G) + 1 < NGRP) ? (G) + 1 : NGRP - 1;                   \
      _Pragma("unroll")                                                        \
      for (int ms = 0; ms < 2; ++ms)                                           \
      _Pragma("unroll")                                                        \
      for (int ks = 0; ks < 4; ++ks)                                           \
          ANXT[ms][ks] = *(const i32x4*)(abase                                 \
              + (size_t)((gn_ * 16 + 2 * wv + ms) * 4 + ks) * 1024); }         \
    /* 4: MFMA + per-group fp32 fold */                                        \
    _Pragma("unroll")                                                          \
    for (int ms = 0; ms < 2; ++ms) {                                           \
        i32x16 ia = {0,0,0,0,0,0,0,0,0,0,0,0,0,0,0,0};                         \
        _Pragma("unroll")                                                      \
        for (int ks = 0; ks < 4; ++ks)                                         \
            ia = __builtin_amdgcn_mfma_i32_32x32x32_i8(ACUR[ms][ks],           \
                                                bf_[ks], ia, 0, 0, 0);         \
        _Pragma("unroll")                                                      \
        for (int r = 0; r < 16; ++r)                                           \
            facc[ms][r] += sg_ * (float)ia[r];                                 \
    }                                                                          \
    /* 5: vmcnt(10) keeps DMA(G+2)x2 + A(G+1)x8 in flight; DMA(G+1) was     */\
    /*    already popped by the compiler's pre-MFMA A(G)-wait.               */\
    __builtin_amdgcn_sched_barrier(0);                                         \
    asm volatile("s_waitcnt vmcnt(10)" ::: "memory");                          \
    __builtin_amdgcn_sched_barrier(0);                                         \
    __builtin_amdgcn_s_barrier();                                              \
    __builtin_amdgcn_sched_barrier(0);                                         \
    /* 6: pack group G+1 (threads 0..255; others fall through) */              \
    if (tid < 256) { PACK_GROUP(WP, ((G) + 1) % 3); }                          \
    /* 7: pack visible to all */                                               \
    asm volatile("s_waitcnt lgkmcnt(0)" ::: "memory");                         \
    __builtin_amdgcn_s_barrier();                                              \
    __builtin_amdgcn_sched_barrier(0);                                         \
} while (0)

__global__ __launch_bounds__(512, 4) void w4a8_gemm(
    const uint8_t* __restrict__ qA, const float* __restrict__ s1,
    const int* __restrict__ w4, const float* __restrict__ sgrp,
    const float* __restrict__ schan, const float* __restrict__ bias,
    float* __restrict__ out)
{
    __shared__ int     raw[3][128 * 32];   // 3 x 16 KB raw int32 w4 ring
    __shared__ uint8_t pk[2][32 * 128];    // 2 x 4 KB packed int8 (col-major)
    __shared__ float   sgl[NGRP * BN];     // 8 KB staged group scales
    // total 64 KB exactly -> 2 workgroups per CU

    const int tid  = threadIdx.x;
    const int lane = tid & 63;
    const int wv   = tid >> 6;        // wave 0..7 -> rows [wv*64, wv*64+64)
    const int l31  = lane & 31;
    const int lhi  = lane >> 5;
    const int n0   = blockIdx.x * BN;
    const int c4   = tid & 7;         // pack: column quad
    const int kq   = tid >> 3;        // pack: k quad (0..31 for tid<256)

    const uint8_t* abase = qA + l31 * 32 + lhi * 16;

    float facc[2][16];
#pragma unroll
    for (int a = 0; a < 2; ++a)
#pragma unroll
    for (int r = 0; r < 16; ++r) facc[a][r] = 0.0f;

    // ---- prologue (champion order: sgl, A(g0), DMA(0), DMA(1)) ----
#pragma unroll
    for (int j = 0; j < 4; ++j) {
        const int idx = tid + j * 512;              // idx = g*32 + c
        sgl[idx] = sgrp[(size_t)(idx >> 5) * N_DIM + n0 + (idx & 31)];
    }

    i32x4 aA[2][4], aB[2][4];
#pragma unroll
    for (int ms = 0; ms < 2; ++ms)
#pragma unroll
    for (int ks = 0; ks < 4; ++ks)
        aA[ms][ks] = *(const i32x4*)(abase + (size_t)((2 * wv + ms) * 4 + ks) * 1024);

    DMA_GROUP(0, 0);
    DMA_GROUP(1, 1);

    __builtin_amdgcn_sched_barrier(0);
    asm volatile("s_waitcnt vmcnt(2)" ::: "memory");  // drain sgl+aA+DMA(0); keep DMA(1)
    __builtin_amdgcn_sched_barrier(0);
    asm volatile("s_waitcnt lgkmcnt(0)" ::: "memory"); // sgl ds_writes visible
    __builtin_amdgcn_s_barrier();
    __builtin_amdgcn_sched_barrier(0);
    if (tid < 256) { PACK_GROUP(0, 0); }
    asm volatile("s_waitcnt lgkmcnt(0)" ::: "memory");
    __builtin_amdgcn_s_barrier();
    __builtin_amdgcn_sched_barrier(0);

    // ---- main loop: ping-pong pk buffers and A-fragment registers ----
#pragma unroll 1
    for (int g = 0; g < NGRP; g += 2) {
        BODY(g,     0, 1, aA, aB);
        BODY(g + 1, 1, 0, aB, aA);
    }

    // ---- epilogue: D = facc * s1[m] * s_channel[n] + bias[n] ----
    {
        const int col = n0 + l31;
        const float sch = schan[col];
        const float bv  = bias[col];
#pragma unroll
        for (int ms = 0; ms < 2; ++ms) {
            const int rbase = wv * 64 + ms * 32 + 4 * lhi;
#pragma unroll
            for (int r = 0; r < 16; ++r) {
                const int row = rbase + (r & 3) + 8 * (r >> 2);
                out[(size_t)row * N_DIM + col] = facc[ms][r] * s1[row] * sch + bv;
            }
        }
    }
}

extern "C" void kernel_launch(void* const* d_in, const int* in_sizes, int n_in,
                              void* d_out, int out_size, void* d_ws, size_t ws_size,
                              hipStream_t stream)
{
    const float* A     = (const float*)d_in[0];
    const int*   w4    = (const int*)  d_in[1];
    const float* sgrp  = (const float*)d_in[2];
    const float* schan = (const float*)d_in[3];
    const float* bias  = (const float*)d_in[4];
    float* out = (float*)d_out;

    // workspace: s1[512] @0, qA (4 MB, fragment-native) @4096
    float*   s1 = (float*)d_ws;
    uint8_t* qA = (uint8_t*)d_ws + 4096;

    quant_rows<<<dim3(M_DIM), dim3(256), 0, stream>>>(A, qA, s1);
    w4a8_gemm<<<dim3(N_DIM / BN), dim3(512), 0, stream>>>(qA, s1, w4, sgrp, schan, bias, out);
}

// Round 15
// 184.337 us; speedup vs baseline: 3.6734x; 3.6734x over previous
//
#include <hip/hip_runtime.h>
#include <stdint.h>

#define M_DIM 512
#define K_DIM 8192
#define N_DIM 14336
#define NGRP  64      // K / 128 groups
#define BN    64      // N columns per workgroup

typedef int   i32x4  __attribute__((ext_vector_type(4)));
typedef int   i32x16 __attribute__((ext_vector_type(16)));
typedef float f32x4  __attribute__((ext_vector_type(4)));

// ---------------- Kernel 1: per-row dynamic int8 quantization ----------------
// Writes qA in MFMA-fragment-native layout:
//   qA[((g*16 + tile)*4 + ks)*1024 + l31*32 + lhi*16 + b]
// where row = tile*32 + l31, k = g*128 + ks*32 + lhi*16 + b.
__global__ __launch_bounds__(256) void quant_rows(const float* __restrict__ A,
                                                  uint8_t* __restrict__ qA,
                                                  float* __restrict__ s1)
{
    const int row  = blockIdx.x;
    const int tid  = threadIdx.x;
    const int tile = row >> 5;
    const int l31  = row & 31;
    const f32x4* src = (const f32x4*)(A + (size_t)row * K_DIM) + tid;

    f32x4 v[8];
#pragma unroll
    for (int i = 0; i < 8; ++i) v[i] = src[i * 256];

    float m = 0.0f;
#pragma unroll
    for (int i = 0; i < 8; ++i)
        m = fmaxf(m, fmaxf(fmaxf(fabsf(v[i].x), fabsf(v[i].y)),
                           fmaxf(fabsf(v[i].z), fabsf(v[i].w))));
#pragma unroll
    for (int off = 32; off > 0; off >>= 1)
        m = fmaxf(m, __shfl_xor(m, off));

    __shared__ float wmax[4];
    if ((tid & 63) == 0) wmax[tid >> 6] = m;
    __syncthreads();
    const float gm = fmaxf(fmaxf(wmax[0], wmax[1]), fmaxf(wmax[2], wmax[3]));
    const float s = gm / 127.0f;   // exact fp32 division, matches reference
    if (tid == 0) s1[row] = s;

#pragma unroll
    for (int i = 0; i < 8; ++i) {
        const int k0  = 4 * (tid + 256 * i);
        const int g   = k0 >> 7;
        const int ks  = (k0 >> 5) & 3;
        const int lhi = (k0 >> 4) & 1;
        const int b   = k0 & 15;
        uint32_t p = 0;
#pragma unroll
        for (int j = 0; j < 4; ++j) {
            float q = rintf(v[i][j] / s);             // round-half-even = np.round
            q = fminf(fmaxf(q, -128.0f), 127.0f);
            p |= ((uint32_t)(uint8_t)(int8_t)(int)q) << (8 * j);
        }
        *(uint32_t*)(qA + (size_t)(g * 16 + tile) * 4096 + ks * 1024
                        + l31 * 32 + lhi * 16 + b) = p;
    }
}

// ---------------- Kernel 2: fused W4A8 GEMM (champion, single-barrier body) --
// Identical to the 184 µs champion (BM=512/8 waves, BN=64, grid 224, ring-3
// raw DMA, pk double-buffer, sgl staged once) EXCEPT the mid-body barrier is
// removed: PACK(G+1) writes pk[WP] while MFMA(G) read pk[RP] — disjoint
// buffers, and pk[WP]'s previous readers (body G-1's bf loads) were forced
// complete by fold(G-1) before the end-of-body barrier. One barrier per group
// lets pack's VALU/LDS ops co-schedule with the MFMA/fold tail and halves the
// 8-wave sync cost.

#define DMA_GROUP(BUF, G) do {                                                 \
    _Pragma("unroll")                                                          \
    for (int j_ = 0; j_ < 4; ++j_) {                                           \
        const int idx_ = j_ * 512 + tid;                                       \
        const int k_   = idx_ >> 4;                                            \
        const int c4_  = idx_ & 15;                                            \
        const int* gsrc_ = w4 + (size_t)((G) * 128 + k_) * N_DIM + n0 + c4_*4; \
        __builtin_amdgcn_global_load_lds(                                      \
            (const __attribute__((address_space(1))) void*)gsrc_,              \
            (__attribute__((address_space(3))) void*)&raw[BUF][(j_*512 + wv*64)*4], \
            16, 0, 0);                                                         \
    }                                                                          \
} while (0)

// pack raw[RBUF] (int32 [k][n]) -> pk[PBUF] (int8 col-major [n][k], swizzled)
#define PACK_GROUP(PBUF, RBUF) do {                                            \
    i32x4 r_[4];                                                               \
    _Pragma("unroll")                                                          \
    for (int j_ = 0; j_ < 4; ++j_)                                             \
        r_[j_] = *(const i32x4*)&raw[RBUF][(kq * 4 + j_) * 64 + c4 * 4];       \
    _Pragma("unroll")                                                          \
    for (int c_ = 0; c_ < 4; ++c_) {                                           \
        const int col_ = c4 * 4 + c_;                                          \
        uint32_t d_ =  ((uint32_t)(r_[0][c_] - 8) & 0xFFu)                     \
                    | (((uint32_t)(r_[1][c_] - 8) & 0xFFu) << 8)               \
                    | (((uint32_t)(r_[2][c_] - 8) & 0xFFu) << 16)              \
                    | (((uint32_t)(r_[3][c_] - 8) & 0xFFu) << 24);             \
        *(uint32_t*)&pk[PBUF][col_ * 128 + ((kq * 4) ^ ((col_ & 7) << 4))] = d_; \
    }                                                                          \
} while (0)

#define BODY(G, RP, WP, ACUR, ANXT) do {                                       \
    /* 1: issue DMA for G+2 */                                                 \
    { const int gd_ = ((G) + 2 < NGRP) ? (G) + 2 : NGRP - 1;                   \
      DMA_GROUP(((G) + 2) % 3, gd_); }                                         \
    /* 2: B fragments + group scales from LDS */                               \
    i32x4 bf_[2][4];                                                           \
    _Pragma("unroll")                                                          \
    for (int nt = 0; nt < 2; ++nt)                                             \
    _Pragma("unroll")                                                          \
    for (int ks = 0; ks < 4; ++ks)                                             \
        bf_[nt][ks] = *(const i32x4*)&pk[RP][(nt*32 + l31) * 128               \
                        + ((ks*32 + lhi*16) ^ ((l31 & 7) << 4))];              \
    const float sg0_ = sgl[(G) * 64 + l31];                                    \
    const float sg1_ = sgl[(G) * 64 + 32 + l31];                               \
    /* 3: prefetch A fragments for G+1 */                                      \
    { const int gn_ = ((G) + 1 < NGRP) ? (G) + 1 : NGRP - 1;                   \
      _Pragma("unroll")                                                        \
      for (int ms = 0; ms < 2; ++ms)                                           \
      _Pragma("unroll")                                                        \
      for (int ks = 0; ks < 4; ++ks)                                           \
          ANXT[ms][ks] = *(const i32x4*)(abase                                 \
              + (size_t)((gn_ * 16 + 2 * wv + ms) * 4 + ks) * 1024); }         \
    /* 4: MFMA + per-group fp32 fold */                                        \
    _Pragma("unroll")                                                          \
    for (int nt = 0; nt < 2; ++nt) {                                           \
        const float sgv_ = nt ? sg1_ : sg0_;                                   \
        _Pragma("unroll")                                                      \
        for (int ms = 0; ms < 2; ++ms) {                                       \
            i32x16 ia = {0,0,0,0,0,0,0,0,0,0,0,0,0,0,0,0};                     \
            _Pragma("unroll")                                                  \
            for (int ks = 0; ks < 4; ++ks)                                     \
                ia = __builtin_amdgcn_mfma_i32_32x32x32_i8(ACUR[ms][ks],       \
                                                    bf_[nt][ks], ia, 0, 0, 0); \
            _Pragma("unroll")                                                  \
            for (int r = 0; r < 16; ++r)                                       \
                facc[ms][nt][r] += sgv_ * (float)ia[r];                        \
        }                                                                      \
    }                                                                          \
    /* 5: vmcnt(12) pops exactly DMA(G+1); DMA(G+2)x4 + A(G+1)x8 stay live */  \
    __builtin_amdgcn_sched_barrier(0);                                         \
    asm volatile("s_waitcnt vmcnt(12)" ::: "memory");                          \
    __builtin_amdgcn_sched_barrier(0);                                         \
    /* 6: pack group G+1 into pk[WP] — disjoint from pk[RP] being read;     */\
    /*    pk[WP]'s old readers completed before last body's barrier.         */\
    PACK_GROUP(WP, ((G) + 1) % 3);                                             \
    /* 7: single barrier: pack visible to all for body G+1 */                  \
    asm volatile("s_waitcnt lgkmcnt(0)" ::: "memory");                         \
    __builtin_amdgcn_s_barrier();                                              \
    __builtin_amdgcn_sched_barrier(0);                                         \
} while (0)

__global__ __launch_bounds__(512) void w4a8_gemm(
    const uint8_t* __restrict__ qA, const float* __restrict__ s1,
    const int* __restrict__ w4, const float* __restrict__ sgrp,
    const float* __restrict__ schan, const float* __restrict__ bias,
    float* __restrict__ out)
{
    __shared__ int     raw[3][128 * 64];   // 3 x 32 KB raw int32 w4 tiles
    __shared__ uint8_t pk[2][64 * 128];    // 2 x 8 KB packed int8 (col-major)
    __shared__ float   sgl[NGRP * BN];     // 16 KB staged group scales

    const int tid  = threadIdx.x;
    const int lane = tid & 63;
    const int wv   = tid >> 6;        // wave 0..7 -> rows [wv*64, wv*64+64)
    const int l31  = lane & 31;
    const int lhi  = lane >> 5;
    const int n0   = blockIdx.x * BN;
    const int c4   = tid & 15;        // pack: column quad
    const int kq   = tid >> 4;        // pack: k quad (0..31)

    const uint8_t* abase = qA + l31 * 32 + lhi * 16;

    float facc[2][2][16];
#pragma unroll
    for (int a = 0; a < 2; ++a)
#pragma unroll
    for (int b = 0; b < 2; ++b)
#pragma unroll
    for (int r = 0; r < 16; ++r) facc[a][b][r] = 0.0f;

    // ---- prologue (champion order: sgl, A(g0), DMA(0), DMA(1)) ----
#pragma unroll
    for (int j = 0; j < 8; ++j) {
        const int idx = tid + j * 512;              // idx = g*64 + c
        sgl[idx] = sgrp[(size_t)(idx >> 6) * N_DIM + n0 + (idx & 63)];
    }

    i32x4 aA[2][4], aB[2][4];
#pragma unroll
    for (int ms = 0; ms < 2; ++ms)
#pragma unroll
    for (int ks = 0; ks < 4; ++ks)
        aA[ms][ks] = *(const i32x4*)(abase + (size_t)((2 * wv + ms) * 4 + ks) * 1024);

    DMA_GROUP(0, 0);
    DMA_GROUP(1, 1);

    __builtin_amdgcn_sched_barrier(0);
    asm volatile("s_waitcnt vmcnt(12)" ::: "memory");  // drain sgl+aA... keep DMA(1)+aA tail
    __builtin_amdgcn_sched_barrier(0);
    asm volatile("s_waitcnt lgkmcnt(0)" ::: "memory"); // sgl ds_writes visible
    __builtin_amdgcn_s_barrier();
    __builtin_amdgcn_sched_barrier(0);
    PACK_GROUP(0, 0);
    asm volatile("s_waitcnt lgkmcnt(0)" ::: "memory");
    __builtin_amdgcn_s_barrier();
    __builtin_amdgcn_sched_barrier(0);

    // ---- main loop: ping-pong pk buffers and A-fragment registers ----
#pragma unroll 1
    for (int g = 0; g < NGRP; g += 2) {
        BODY(g,     0, 1, aA, aB);
        BODY(g + 1, 1, 0, aB, aA);
    }

    // ---- epilogue: D = facc * s1[m] * s_channel[n] + bias[n] ----
#pragma unroll
    for (int nt = 0; nt < 2; ++nt) {
        const int col = n0 + nt * 32 + l31;
        const float sch = schan[col];
        const float bv  = bias[col];
#pragma unroll
        for (int ms = 0; ms < 2; ++ms) {
            const int rbase = wv * 64 + ms * 32 + 4 * lhi;
#pragma unroll
            for (int r = 0; r < 16; ++r) {
                const int row = rbase + (r & 3) + 8 * (r >> 2);
                out[(size_t)row * N_DIM + col] = facc[ms][nt][r] * s1[row] * sch + bv;
            }
        }
    }
}

extern "C" void kernel_launch(void* const* d_in, const int* in_sizes, int n_in,
                              void* d_out, int out_size, void* d_ws, size_t ws_size,
                              hipStream_t stream)
{
    const float* A     = (const float*)d_in[0];
    const int*   w4    = (const int*)  d_in[1];
    const float* sgrp  = (const float*)d_in[2];
    const float* schan = (const float*)d_in[3];
    const float* bias  = (const float*)d_in[4];
    float* out = (float*)d_out;

    // workspace: s1[512] @0, qA (4 MB, fragment-native) @4096
    float*   s1 = (float*)d_ws;
    uint8_t* qA = (uint8_t*)d_ws + 4096;

    quant_rows<<<dim3(M_DIM), dim3(256), 0, stream>>>(A, qA, s1);
    w4a8_gemm<<<dim3(N_DIM / BN), dim3(512), 0, stream>>>(qA, s1, w4, sgrp, schan, bias, out);
}